// Round 9
// baseline (193.477 us; speedup 1.0000x reference)
//
#include <hip/hip_runtime.h>

// ============================================================================
// INSTRUMENTATION ROUND — measurement, not optimization.
// Identical to the best kernel (R1, 159.3 us) EXCEPT every plane is processed
// TWICE (grid.y = 512, bz = blockIdx.y & 255). Duplicate blocks write byte-
// identical values (benign race; output deterministic; absmax unchanged).
// Purpose:
//   1) dur(2x) - dur(1x) = TRUE kernel device time (never directly observed:
//      the kan kernel has never appeared in the top-5 counter table, so all
//      session conclusions rest on an unverified dur = fill + kernel split).
//   2) At ~2x duration the kernel should finally outrank the ~80 us harness
//      fills in the counter table, surfacing its VALUBusy / Occupancy /
//      FETCH_SIZE / SQ_LDS_BANK_CONFLICT / VGPR_Count for the first time.
// ============================================================================

#define BATCH 16
#define CH    16
#define HH    128
#define WW    128
#define NC    8            // n_convs
#define TR    8            // output rows per band
#define BPB   4            // bands per block (persistent over 4 bands)
#define HR    (TR + 2)     // 10 halo rows
#define FW    (WW + 2)     // 130 halo cols
#define NELEM (HR * FW)    // 1300 staged elements per band
#define NSTG  ((NELEM + 255) / 256)   // 6 staging slots per thread

// Per-element features: f0=silu(v), f1=tanh(v), f2=2t^2 (=T2+1), f3=T3=4t^3-3t.
// bias_j = sum_i (W0 - W2)[j,i] absorbs T0 and the +1 shift of f2, so features
// are exactly (0,0,0,0) at v=0 -> zero padding handled by feat(0)=0.
__global__ __launch_bounds__(256, 4)
void kan_conv_kernel(const float* __restrict__ x,
                     const float* __restrict__ cheby,   // (8,9,4)
                     const float* __restrict__ bwt,     // (8,9)
                     const float* __restrict__ scl,     // (8,9)
                     float* __restrict__ out)           // (16,128,128,128)
{
    __shared__ float4 feat[HR][FW];      // 20,800 B
    __shared__ float4 wgt[9 * NC];       // [tap*8 + j] = (bw, W1, W2, W3)
    __shared__ float  bias[NC];

    const int tid   = threadIdx.x;       // 0..255
    const int bz    = blockIdx.y & 255;  // plane, processed by TWO blocks
    const int band0 = blockIdx.x * (TR * BPB);

    const float* xp = x + (size_t)bz * HH * WW;

    // ---- stage combined weights (once per 4 bands) ----
    if (tid < 9 * NC) {
        int j = tid / 9, i = tid % 9;
        float s = scl[j * 9 + i];
        wgt[i * NC + j] = make_float4(bwt[j * 9 + i],
                                      cheby[(j * 9 + i) * 4 + 1] * s,
                                      cheby[(j * 9 + i) * 4 + 2] * s,
                                      cheby[(j * 9 + i) * 4 + 3] * s);
    } else if (tid >= 128 && tid < 128 + NC) {
        int j = tid - 128;
        float b = 0.f;
        #pragma unroll
        for (int i = 0; i < 9; ++i)
            b += (cheby[(j * 9 + i) * 4 + 0] - cheby[(j * 9 + i) * 4 + 2]) * scl[j * 9 + i];
        bias[j] = b;
    }

    // ---- issue band-0 staging loads back-to-back into registers ----
    float v[NSTG];
    #pragma unroll
    for (int k = 0; k < NSTG; ++k) {
        int idx = tid + 256 * k;
        int row = idx / FW;              // magic-mul div
        int col = idx - row * FW;
        int gh  = band0 + row - 1;
        int gw  = col - 1;
        float nv = 0.f;
        if (idx < NELEM && (unsigned)gh < (unsigned)HH && (unsigned)gw < (unsigned)WW)
            nv = xp[gh * WW + gw];       // 4B/lane coalesced
        v[k] = nv;
    }

    for (int bb = 0; bb < BPB; ++bb) {
        const int band = band0 + bb * TR;

        // ---- features from prefetched registers -> LDS ----
        #pragma unroll
        for (int k = 0; k < NSTG; ++k) {
            int idx = tid + 256 * k;
            if (idx < NELEM) {
                int row = idx / FW;
                int col = idx - row * FW;
                float val = v[k];
                float e1 = __expf(val);
                float e2 = e1 * e1;                               // exp(2v)
                float sg = 1.f - __builtin_amdgcn_rcpf(1.f + e1); // sigmoid(v)
                float t  = 1.f - 2.f * __builtin_amdgcn_rcpf(e2 + 1.f); // tanh(v)
                float f2 = 2.f * t * t;                           // T2 + 1
                float f3 = 2.f * t * (f2 - 1.f) - t;              // T3
                feat[row][col] = make_float4(val * sg, t, f2, f3);
            }
        }
        __syncthreads();

        // ---- prefetch next band's x while this band's conv runs ----
        if (bb + 1 < BPB) {
            const int nb = band + TR;
            #pragma unroll
            for (int k = 0; k < NSTG; ++k) {
                int idx = tid + 256 * k;
                int row = idx / FW;
                int col = idx - row * FW;
                int gh  = nb + row - 1;
                int gw  = col - 1;
                float nv = 0.f;
                if (idx < NELEM && (unsigned)gh < (unsigned)HH && (unsigned)gw < (unsigned)WW)
                    nv = xp[gh * WW + gw];
                v[k] = nv;
            }
        }

        // ---- conv: thread owns col c, rows r0+2s (s=0..3); taps unrolled ----
        const int c  = tid & 127;            // 0..127
        const int r0 = tid >> 7;             // 0..1

        float acc[4][NC];                    // 32 VGPRs — fits, no spill
        #pragma unroll
        for (int s = 0; s < 4; ++s)
            #pragma unroll
            for (int j = 0; j < NC; ++j)
                acc[s][j] = bias[j];

        #pragma unroll
        for (int dr = 0; dr < 3; ++dr) {
            #pragma unroll
            for (int dc = 0; dc < 3; ++dc) {
                float4 f[4];
                #pragma unroll
                for (int s = 0; s < 4; ++s)
                    f[s] = feat[r0 + 2 * s + dr][c + dc];   // 16B/lane: conflict-free
                #pragma unroll
                for (int j = 0; j < NC; ++j) {
                    float4 w = wgt[(dr * 3 + dc) * NC + j]; // uniform broadcast
                    #pragma unroll
                    for (int s = 0; s < 4; ++s) {
                        acc[s][j] += w.x * f[s].x;
                        acc[s][j] += w.y * f[s].y;
                        acc[s][j] += w.z * f[s].z;
                        acc[s][j] += w.w * f[s].w;
                    }
                }
            }
        }

        // ---- store: each wave writes 64 consecutive floats (256B contiguous) ----
        float* op = out + (size_t)(bz * NC) * HH * WW + (size_t)(band + r0) * WW + c;
        #pragma unroll
        for (int j = 0; j < NC; ++j)
            #pragma unroll
            for (int s = 0; s < 4; ++s)
                op[(size_t)j * HH * WW + s * 2 * WW] = acc[s][j];

        __syncthreads();   // feat[] reuse guard for next band
    }
}

extern "C" void kernel_launch(void* const* d_in, const int* in_sizes, int n_in,
                              void* d_out, int out_size, void* d_ws, size_t ws_size,
                              hipStream_t stream) {
    const float* x     = (const float*)d_in[0];
    const float* cheby = (const float*)d_in[1];
    const float* bwt   = (const float*)d_in[2];
    const float* scl   = (const float*)d_in[3];
    float* out = (float*)d_out;

    // INSTRUMENTATION: grid.y doubled; every plane computed twice with
    // identical results. dur(2x) - dur(1x at R1=159.3) = true kernel time.
    dim3 grid(HH / (TR * BPB), 2 * BATCH * CH);  // 4 x 512 = 2048 blocks
    dim3 block(256);
    hipLaunchKernelGGL(kan_conv_kernel, grid, block, 0, stream, x, cheby, bwt, scl, out);
}